// Round 1
// baseline (327.771 us; speedup 1.0000x reference)
//
#include <hip/hip_runtime.h>

#define N_NODES 16384
#define N_EDGES 262144
#define EP (N_EDGES + N_NODES)   // with self-loops
#define HID 128
#define ENC 768
#define NEG 0.2f
#define EPSV 1e-5f

__device__ __forceinline__ float wave_sum(float v){
  #pragma unroll
  for(int m=32;m>=1;m>>=1) v += __shfl_xor(v, m, 64);
  return v;
}
__device__ __forceinline__ float lrelu(float v){ return v > 0.f ? v : NEG*v; }

// ---- input transforms for layer 1: xl1 = x@W1l+b1l, xr1 = x@W1r+b1r ----
__global__ __launch_bounds__(256) void lin1_kernel(
    const float* __restrict__ x,
    const float* __restrict__ Wl, const float* __restrict__ bl,
    const float* __restrict__ Wr, const float* __restrict__ br,
    float* __restrict__ xl1, float* __restrict__ xr1){
  const int i = blockIdx.x*256 + threadIdx.x;        // exactly N*HID threads
  const int n = i >> 7, c = i & 127;
  const float x0 = x[n*3], x1 = x[n*3+1], x2 = x[n*3+2];
  xl1[i] = x0*Wl[c] + x1*Wl[HID+c] + x2*Wl[2*HID+c] + bl[c];
  xr1[i] = x0*Wr[c] + x1*Wr[HID+c] + x2*Wr[2*HID+c] + br[c];
}

// ---- CSR build: histogram of dst ----
__global__ __launch_bounds__(256) void hist_kernel(
    const int* __restrict__ ei, int* __restrict__ hist){
  const int i = blockIdx.x*256 + threadIdx.x;        // exactly EP threads
  const int dst = (i < N_EDGES) ? ei[N_EDGES + i] : (i - N_EDGES);
  atomicAdd(&hist[dst], 1);
}

// ---- single-block exclusive scan over N=16384 (1024 thr x 16 items) ----
__global__ __launch_bounds__(1024) void scan_kernel(
    const int* __restrict__ hist, int* __restrict__ rowstart){
  __shared__ int sums[1024];
  const int t = threadIdx.x;
  const int base = t*16;
  int loc[16];
  int s = 0;
  #pragma unroll
  for(int i=0;i<16;i++){ loc[i] = s; s += hist[base+i]; }
  sums[t] = s;
  __syncthreads();
  for(int off=1; off<1024; off<<=1){
    int v = 0;
    if(t >= off) v = sums[t-off];
    __syncthreads();
    if(t >= off) sums[t] += v;
    __syncthreads();
  }
  const int prev = (t==0) ? 0 : sums[t-1];
  #pragma unroll
  for(int i=0;i<16;i++) rowstart[base+i] = prev + loc[i];
  if(t == 1023) rowstart[N_NODES] = EP;
}

// ---- CSR build: scatter src ids into dst-sorted order ----
__global__ __launch_bounds__(256) void scatter_kernel(
    const int* __restrict__ ei, const int* __restrict__ rowstart,
    int* __restrict__ cursor, int* __restrict__ ssrc){
  const int i = blockIdx.x*256 + threadIdx.x;        // exactly EP threads
  const int src = (i < N_EDGES) ? ei[i]           : (i - N_EDGES);
  const int dst = (i < N_EDGES) ? ei[N_EDGES + i] : (i - N_EDGES);
  const int pos = rowstart[dst] + atomicAdd(&cursor[dst], 1);
  ssrc[pos] = src;
}

// ---- GAT layer 1 per-node: score+softmax+aggregate+bias+LN+ELU, 1 wave/node ----
__global__ __launch_bounds__(256) void node1_kernel(
    const float* __restrict__ xl1, const float* __restrict__ xr1,
    const float* __restrict__ att1, const float* __restrict__ bias1,
    const float* __restrict__ g1, const float* __restrict__ b1,
    const int* __restrict__ rowstart, const int* __restrict__ ssrc,
    float* __restrict__ h1){
  const int lane = threadIdx.x & 63;
  const int n = blockIdx.x*4 + (threadIdx.x >> 6);
  const int c0 = lane, c1 = lane + 64;
  const float xra = xr1[n*HID+c0], xrb = xr1[n*HID+c1];
  const float aa = att1[c0], ab = att1[c1];
  float acc0 = 0.f, acc1 = 0.f, denom = 0.f;
  const int p0 = rowstart[n], p1 = rowstart[n+1];
  for(int p=p0; p<p1; ++p){
    const int s = ssrc[p];
    const float v0 = xl1[s*HID+c0], v1 = xl1[s*HID+c1];
    const float e = wave_sum(lrelu(v0+xra)*aa + lrelu(v1+xrb)*ab);
    const float w = expf(e);              // max-shift cancels in alpha; |e| small
    denom += w; acc0 += w*v0; acc1 += w*v1;
  }
  const float inv = 1.f/denom;
  const float y0 = acc0*inv + bias1[c0];
  const float y1 = acc1*inv + bias1[c1];
  const float mu  = wave_sum(y0+y1) * (1.f/HID);
  const float d0 = y0-mu, d1 = y1-mu;
  const float var = wave_sum(d0*d0 + d1*d1) * (1.f/HID);
  const float r = rsqrtf(var + EPSV);
  float z0 = d0*r*g1[c0] + b1[c0];
  float z1 = d1*r*g1[c1] + b1[c1];
  z0 = z0 > 0.f ? z0 : expm1f(z0);        // ELU(alpha=1)
  z1 = z1 > 0.f ? z1 : expm1f(z1);
  h1[n*HID+c0] = z0; h1[n*HID+c1] = z1;
}

// ---- layer-2 transforms: xl2 = h1@W2l+b2l, xr2 = h1@W2r+b2r (tiled, 8 nodes/blk) ----
#define TM 8
__global__ __launch_bounds__(256) void lin2_kernel(
    const float* __restrict__ h1,
    const float* __restrict__ Wl, const float* __restrict__ bl,
    const float* __restrict__ Wr, const float* __restrict__ br,
    float* __restrict__ xl2, float* __restrict__ xr2){
  __shared__ float hs[TM][HID];
  const int tid = threadIdx.x;
  const int nb = blockIdx.x * TM;
  for(int i=tid; i<TM*HID; i+=256) hs[i>>7][i&127] = h1[nb*HID + i];
  __syncthreads();
  float accl[TM][3] = {}; float accr[TM][3] = {};
  const int c0 = tid, c1 = tid+256, c2 = tid+512;
  for(int k=0; k<HID; ++k){
    const float wl0=Wl[k*ENC+c0], wl1=Wl[k*ENC+c1], wl2=Wl[k*ENC+c2];
    const float wr0=Wr[k*ENC+c0], wr1=Wr[k*ENC+c1], wr2=Wr[k*ENC+c2];
    #pragma unroll
    for(int nn=0; nn<TM; ++nn){
      const float hv = hs[nn][k];
      accl[nn][0] += hv*wl0; accl[nn][1] += hv*wl1; accl[nn][2] += hv*wl2;
      accr[nn][0] += hv*wr0; accr[nn][1] += hv*wr1; accr[nn][2] += hv*wr2;
    }
  }
  const float bl0=bl[c0], bl1=bl[c1], bl2=bl[c2];
  const float br0=br[c0], br1=br[c1], br2=br[c2];
  #pragma unroll
  for(int nn=0; nn<TM; ++nn){
    const size_t row = (size_t)(nb+nn)*ENC;
    xl2[row+c0]=accl[nn][0]+bl0; xl2[row+c1]=accl[nn][1]+bl1; xl2[row+c2]=accl[nn][2]+bl2;
    xr2[row+c0]=accr[nn][0]+br0; xr2[row+c1]=accr[nn][1]+br1; xr2[row+c2]=accr[nn][2]+br2;
  }
}

// ---- GAT layer 2 per-node + bias2 + inline residual (x@Wfc+bfc) + final LN ----
__global__ __launch_bounds__(256) void node2_kernel(
    const float* __restrict__ xl2, const float* __restrict__ xr2,
    const float* __restrict__ att2, const float* __restrict__ bias2,
    const float* __restrict__ x, const float* __restrict__ Wfc,
    const float* __restrict__ bfc,
    const float* __restrict__ gn, const float* __restrict__ bn,
    const int* __restrict__ rowstart, const int* __restrict__ ssrc,
    float* __restrict__ out){
  const int lane = threadIdx.x & 63;
  const int n = blockIdx.x*4 + (threadIdx.x >> 6);
  float xr[12], at[12], acc[12];
  const float* xrrow = xr2 + (size_t)n*ENC;
  #pragma unroll
  for(int j=0;j<12;j++){ const int c = lane + 64*j; xr[j]=xrrow[c]; at[j]=att2[c]; acc[j]=0.f; }
  float denom = 0.f;
  const int p0 = rowstart[n], p1 = rowstart[n+1];
  for(int p=p0; p<p1; ++p){
    const int s = ssrc[p];
    const float* xlrow = xl2 + (size_t)s*ENC;
    float v[12]; float partial = 0.f;
    #pragma unroll
    for(int j=0;j<12;j++) v[j] = xlrow[lane + 64*j];
    #pragma unroll
    for(int j=0;j<12;j++) partial += lrelu(v[j]+xr[j])*at[j];
    const float e = wave_sum(partial);
    const float w = expf(e);
    denom += w;
    #pragma unroll
    for(int j=0;j<12;j++) acc[j] += w*v[j];
  }
  const float inv = 1.f/denom;
  const float x0 = x[n*3], x1 = x[n*3+1], x2 = x[n*3+2];
  float ys = 0.f;
  #pragma unroll
  for(int j=0;j<12;j++){
    const int c = lane + 64*j;
    const float res = x0*Wfc[c] + x1*Wfc[ENC+c] + x2*Wfc[2*ENC+c] + bfc[c];
    acc[j] = acc[j]*inv + bias2[c] + res;
    ys += acc[j];
  }
  const float mu = wave_sum(ys) * (1.f/ENC);
  float vs = 0.f;
  #pragma unroll
  for(int j=0;j<12;j++){ const float d = acc[j]-mu; vs += d*d; }
  const float var = wave_sum(vs) * (1.f/ENC);
  const float r = rsqrtf(var + EPSV);
  float* orow = out + (size_t)n*ENC;
  #pragma unroll
  for(int j=0;j<12;j++){
    const int c = lane + 64*j;
    orow[c] = (acc[j]-mu)*r*gn[c] + bn[c];
  }
}

extern "C" void kernel_launch(void* const* d_in, const int* in_sizes, int n_in,
                              void* d_out, int out_size, void* d_ws, size_t ws_size,
                              hipStream_t stream) {
  const float* x    = (const float*)d_in[0];
  const int*   ei   = (const int*)  d_in[1];
  const float* Wfc  = (const float*)d_in[2];
  const float* bfc  = (const float*)d_in[3];
  const float* W1l  = (const float*)d_in[4];
  const float* b1l  = (const float*)d_in[5];
  const float* W1r  = (const float*)d_in[6];
  const float* b1r  = (const float*)d_in[7];
  const float* att1 = (const float*)d_in[8];
  const float* bias1= (const float*)d_in[9];
  const float* g1   = (const float*)d_in[10];
  const float* bb1  = (const float*)d_in[11];
  const float* W2l  = (const float*)d_in[12];
  const float* b2l  = (const float*)d_in[13];
  const float* W2r  = (const float*)d_in[14];
  const float* b2r  = (const float*)d_in[15];
  const float* att2 = (const float*)d_in[16];
  const float* bias2= (const float*)d_in[17];
  const float* gn   = (const float*)d_in[18];
  const float* bn   = (const float*)d_in[19];
  float* out = (float*)d_out;

  char* w = (char*)d_ws;
  auto alloc = [&](size_t bytes){ void* p = (void*)w; w += (bytes + 255) & ~(size_t)255; return p; };
  int*   hist     = (int*)  alloc((size_t)N_NODES*4);      // contiguous with cursor
  int*   cursor   = (int*)  alloc((size_t)N_NODES*4);
  int*   rowstart = (int*)  alloc((size_t)(N_NODES+1)*4);
  int*   ssrc     = (int*)  alloc((size_t)EP*4);
  float* xl1      = (float*)alloc((size_t)N_NODES*HID*4);
  float* xr1      = (float*)alloc((size_t)N_NODES*HID*4);
  float* h1       = (float*)alloc((size_t)N_NODES*HID*4);
  float* xl2      = (float*)alloc((size_t)N_NODES*ENC*4);
  float* xr2      = (float*)alloc((size_t)N_NODES*ENC*4);

  // zero hist + cursor (adjacent, both N ints, 256B-aligned sizes)
  hipMemsetAsync(hist, 0, (size_t)N_NODES*8, stream);

  lin1_kernel<<<N_NODES*HID/256, 256, 0, stream>>>(x, W1l, b1l, W1r, b1r, xl1, xr1);
  hist_kernel<<<EP/256, 256, 0, stream>>>(ei, hist);
  scan_kernel<<<1, 1024, 0, stream>>>(hist, rowstart);
  scatter_kernel<<<EP/256, 256, 0, stream>>>(ei, rowstart, cursor, ssrc);
  node1_kernel<<<N_NODES/4, 256, 0, stream>>>(xl1, xr1, att1, bias1, g1, bb1,
                                              rowstart, ssrc, h1);
  lin2_kernel<<<N_NODES/TM, 256, 0, stream>>>(h1, W2l, b2l, W2r, b2r, xl2, xr2);
  node2_kernel<<<N_NODES/4, 256, 0, stream>>>(xl2, xr2, att2, bias2,
                                              x, Wfc, bfc, gn, bn,
                                              rowstart, ssrc, out);
}